// Round 13
// baseline (107.191 us; speedup 1.0000x reference)
//
#include <hip/hip_runtime.h>
#include <hip/hip_bf16.h>

#define Bn 64
#define Cn 2048
#define Nn 162          // H*W = 18*9
#define Pn 81           // Nn/2
#define NP 176          // padded N for featT rows (11 tiles of 16)
#define INFV 1.0e9f
#define BIGI 0x7FFFFFFF
#define RBW 328         // k_hung LDS cost-row stride BYTES
#define ARRCAP 700

// ws layout (in floats)
// featT layout: [b][cc(32)][gcol(NP)][32 u32]  (cc = 64-channel chunk)
#define OFF_T    0                           // bf16 featT = 11,534,336 floats
#define OFF_P    11534336                    // [64][32][192] norm^2 partials
#define OFF_QS   (OFF_P + 64*32*192)         // (unused, layout keep)
#define OFF_KS   (OFF_QS + 64*162)           // (unused, layout keep)
#define OFF_COST (OFF_KS + 64*162)           // [64][162][162] RAW sim (fp32)
#define OFF_PD   (OFF_COST + 64*162*162)     // [64] per-batch pos_dis

typedef __attribute__((ext_vector_type(8))) short bf16x8;
typedef __attribute__((ext_vector_type(4))) float f32x4;
typedef __attribute__((ext_vector_type(4))) unsigned u32x4;

static __device__ __forceinline__ unsigned short f2bf(float x) {
    unsigned int u = __builtin_bit_cast(unsigned int, x);
    unsigned int r = (u + 0x7fffu + ((u >> 16) & 1u)) >> 16;   // RNE
    return (unsigned short)r;
}
static __device__ __forceinline__ unsigned short f2h(float x) {
    _Float16 h = (_Float16)x;
    return __builtin_bit_cast(unsigned short, h);
}
static __device__ __forceinline__ float h2f(unsigned short u) {
    return (float)__builtin_bit_cast(_Float16, u);
}
static __device__ __forceinline__ unsigned umin32(unsigned a, unsigned b) { return a < b ? a : b; }
static __device__ __forceinline__ unsigned umax32(unsigned a, unsigned b) { return a > b ? a : b; }
static __device__ __forceinline__ unsigned packnn(float v, int id) {
    float c = fmaxf(v, 0.f);
    return (__builtin_bit_cast(unsigned, c) & 0xFFFFFF00u) | (unsigned)id;
}
static __device__ __forceinline__ float unpacknn(unsigned pk) {
    return __builtin_bit_cast(float, pk & 0xFFFFFF00u);
}
static __device__ __forceinline__ unsigned reduceMin64(unsigned x) {
    int v = (int)x, t;
    t = __builtin_amdgcn_update_dpp(0, v, 0x121, 0xF, 0xF, true); v = (int)umin32((unsigned)v, (unsigned)t);
    t = __builtin_amdgcn_update_dpp(0, v, 0x122, 0xF, 0xF, true); v = (int)umin32((unsigned)v, (unsigned)t);
    t = __builtin_amdgcn_update_dpp(0, v, 0x124, 0xF, 0xF, true); v = (int)umin32((unsigned)v, (unsigned)t);
    t = __builtin_amdgcn_update_dpp(0, v, 0x128, 0xF, 0xF, true); v = (int)umin32((unsigned)v, (unsigned)t);
    unsigned a = (unsigned)__builtin_amdgcn_readlane(v, 0);
    unsigned b = (unsigned)__builtin_amdgcn_readlane(v, 16);
    unsigned c = (unsigned)__builtin_amdgcn_readlane(v, 32);
    unsigned d = (unsigned)__builtin_amdgcn_readlane(v, 48);
    return umin32(umin32(a, b), umin32(c, d));
}
static __device__ __forceinline__ int rlanei(int v, int l) { return __builtin_amdgcn_readlane(v, l); }
static __device__ __forceinline__ float rlanef(float v, int l) {
    return __builtin_bit_cast(float, __builtin_amdgcn_readlane(__builtin_bit_cast(int, v), l));
}
static __device__ __forceinline__ int laneOf(int id) { return id < 128 ? (id >> 1) : (id - 128); }
static __device__ __forceinline__ int slotOf(int id) { return id < 128 ? (id & 1) : 2; }
static __device__ __forceinline__ unsigned long long mask_n(int n) {
    if (n <= 0) return 0ull;
    if (n >= 64) return ~0ull;
    return (1ull << n) - 1ull;
}
#define SEL3(s, a0, a1, a2) ((s) == 0 ? (a0) : ((s) == 1 ? (a1) : (a2)))

// ---------------- K1 v4: fully-contiguous transpose + norm^2 ----------------
// Block (cc,b): reads ONE contiguous 41.5KB fp32 region (64 adjacent ch-rows),
// builds bf16 LDS tile, re-reads per-col from L2 for deterministic norm^2,
// writes ONE contiguous 22.5KB featT slab.
__global__ __launch_bounds__(256) void k_tr(const float* __restrict__ feat, float* __restrict__ ws) {
    int cc = blockIdx.x;           // 0..31 channel chunk
    int b  = blockIdx.y;
    int tid = threadIdx.x;
    __shared__ unsigned Ld[64][83];           // [ch][col-pair] packed bf16 (cols c,c+1)
    const float* fb = feat + ((size_t)b * Cn + (size_t)cc * 64) * Nn;   // contiguous 10368 floats

    // ---- Phase A: flat coalesced read + LDS build (2592 float4) ----
    #pragma unroll
    for (int it = 0; it < 10; ++it) {
        int k = it * 256 + tid;
        float4 v = *(const float4*)(fb + 4 * k);
        int qa = 4 * k;             // pair A: cols (qa%162, +1), ch = qa/162
        int qb = qa + 2;
        int cha = (unsigned)qa / 162u, cola = qa - cha * 162;
        int chb = (unsigned)qb / 162u, colb = qb - chb * 162;
        Ld[cha][cola >> 1] = (unsigned)f2bf(v.x) | ((unsigned)f2bf(v.y) << 16);
        Ld[chb][colb >> 1] = (unsigned)f2bf(v.z) | ((unsigned)f2bf(v.w) << 16);
    }
    if (tid < 32) {
        int k = 2560 + tid;
        float4 v = *(const float4*)(fb + 4 * k);
        int qa = 4 * k, qb = qa + 2;
        int cha = (unsigned)qa / 162u, cola = qa - cha * 162;
        int chb = (unsigned)qb / 162u, colb = qb - chb * 162;
        Ld[cha][cola >> 1] = (unsigned)f2bf(v.x) | ((unsigned)f2bf(v.y) << 16);
        Ld[chb][colb >> 1] = (unsigned)f2bf(v.z) | ((unsigned)f2bf(v.w) << 16);
    }

    // ---- Phase B: deterministic fp32 norm^2 partial per column (L2-hot re-read) ----
    if (tid < Nn) {
        float s0 = 0.f, s1 = 0.f, s2 = 0.f, s3 = 0.f;
        #pragma unroll 4
        for (int ch = 0; ch < 64; ch += 4) {
            float a0 = fb[(size_t)ch * Nn + tid];
            float a1 = fb[(size_t)(ch + 1) * Nn + tid];
            float a2 = fb[(size_t)(ch + 2) * Nn + tid];
            float a3 = fb[(size_t)(ch + 3) * Nn + tid];
            s0 = fmaf(a0, a0, s0);
            s1 = fmaf(a1, a1, s1);
            s2 = fmaf(a2, a2, s2);
            s3 = fmaf(a3, a3, s3);
        }
        ws[OFF_P + ((size_t)b * 32 + cc) * 192 + tid] = (s0 + s1) + (s2 + s3);
    }
    __syncthreads();

    // ---- Phase C: contiguous 22.5KB featT slab write ----
    unsigned* ft = (unsigned*)(ws + OFF_T);
    size_t base = (size_t)(b * 32 + cc) * NP * 32;
    #pragma unroll
    for (int it = 0; it < 22; ++it) {
        int idx = it * 256 + tid;               // 0..5631
        int p = idx & 31, gcol = idx >> 5;
        unsigned outw = 0u;
        if (gcol < Nn) {
            unsigned w0 = Ld[2 * p][gcol >> 1];
            unsigned w1 = Ld[2 * p + 1][gcol >> 1];
            if (gcol & 1) { outw = (w0 >> 16) | (w1 & 0xFFFF0000u); }
            else          { outw = (w0 & 0xFFFFu) | (w1 << 16); }
        }
        ft[base + idx] = outw;
    }
}

// ---------------- K2: bf16 MFMA GEMM from featT -> RAW sim ----------------
// featT [b][cc][gcol][8 granules of 16B]; granule gg: cc=gg>>3, g'=gg&7.
__global__ __launch_bounds__(256) void k_mm(const int* __restrict__ pos_ind,
                                            float* __restrict__ ws) {
    int wg = blockIdx.x;
    int xcd = wg & 7, kk = wg >> 3;
    int b  = xcd + 8 * (kk / 6);
    int mt = kk % 6;
    int tid = threadIdx.x;
    int lane = tid & 63, w = tid >> 6;
    int q0 = mt * 32;
    int pb = pos_ind[b];
    const u32x4* At = (const u32x4*)((const unsigned short*)(ws + OFF_T) + (size_t)b  * NP * Cn);
    const u32x4* Bt = (const u32x4*)((const unsigned short*)(ws + OFF_T) + (size_t)pb * NP * Cn);
    __shared__ u32x4 As[32 * 16];      // 8 KB
    __shared__ u32x4 Bs[176 * 16];     // 44 KB

    f32x4 a00 = {0.f, 0.f, 0.f, 0.f}, a01 = a00, a02 = a00, a10 = a00, a11 = a00, a12 = a00;
    const int ct0 = w * 3, ct1 = w * 3 + 1, ct2 = w * 3 + 2;
    const bool has2 = (ct2 < 11);
    const int fr = lane & 15, fq = lane >> 4;

    for (int c0 = 0; c0 < Cn; c0 += 128) {
        int cc0 = c0 >> 6;
        #pragma unroll
        for (int it = 0; it < 2; ++it) {
            int task = it * 256 + tid;
            int r = task >> 4, g = task & 15;
            int rowc = q0 + r; if (rowc > NP - 1) rowc = NP - 1;
            As[r * 16 + (g ^ (r & 15))] = At[((size_t)(cc0 + (g >> 3)) * NP + rowc) * 8 + (g & 7)];
        }
        #pragma unroll
        for (int it = 0; it < 11; ++it) {
            int task = it * 256 + tid;
            int col = task >> 4, g = task & 15;
            Bs[col * 16 + (g ^ (col & 15))] = Bt[((size_t)(cc0 + (g >> 3)) * NP + col) * 8 + (g & 7)];
        }
        __syncthreads();
        #pragma unroll
        for (int ks = 0; ks < 4; ++ks) {
            int gk = ks * 4 + fq;
            bf16x8 af0 = *(const bf16x8*)&As[fr * 16 + (gk ^ fr)];
            bf16x8 af1 = *(const bf16x8*)&As[(16 + fr) * 16 + (gk ^ fr)];
            bf16x8 b0 = *(const bf16x8*)&Bs[(ct0 * 16 + fr) * 16 + (gk ^ fr)];
            bf16x8 b1 = *(const bf16x8*)&Bs[(ct1 * 16 + fr) * 16 + (gk ^ fr)];
            a00 = __builtin_amdgcn_mfma_f32_16x16x32_bf16(af0, b0, a00, 0, 0, 0);
            a01 = __builtin_amdgcn_mfma_f32_16x16x32_bf16(af0, b1, a01, 0, 0, 0);
            a10 = __builtin_amdgcn_mfma_f32_16x16x32_bf16(af1, b0, a10, 0, 0, 0);
            a11 = __builtin_amdgcn_mfma_f32_16x16x32_bf16(af1, b1, a11, 0, 0, 0);
            if (has2) {
                bf16x8 b2 = *(const bf16x8*)&Bs[(ct2 * 16 + fr) * 16 + (gk ^ fr)];
                a02 = __builtin_amdgcn_mfma_f32_16x16x32_bf16(af0, b2, a02, 0, 0, 0);
                a12 = __builtin_amdgcn_mfma_f32_16x16x32_bf16(af1, b2, a12, 0, 0, 0);
            }
        }
        __syncthreads();
    }

    float* simg = ws + OFF_COST + (size_t)b * Nn * Nn;
    int c0_ = ct0 * 16 + fr, c1_ = ct1 * 16 + fr, c2_ = ct2 * 16 + fr;
    #pragma unroll
    for (int j = 0; j < 4; ++j) {
        int r0 = q0 + fq * 4 + j;
        int r1 = r0 + 16;
        if (r0 < Nn) {
            if (c0_ < Nn) simg[(size_t)r0 * Nn + c0_] = a00[j];
            if (c1_ < Nn) simg[(size_t)r0 * Nn + c1_] = a01[j];
            if (has2 && c2_ < Nn) simg[(size_t)r0 * Nn + c2_] = a02[j];
        }
        if (r1 < Nn) {
            if (c0_ < Nn) simg[(size_t)r1 * Nn + c0_] = a10[j];
            if (c1_ < Nn) simg[(size_t)r1 * Nn + c1_] = a11[j];
            if (has2 && c2_ < Nn) simg[(size_t)r1 * Nn + c2_] = a12[j];
        }
    }
}

// ---------------- K3: fused stats + rectangular LAPJV ----------------
__global__ __launch_bounds__(256) void k_hung(float* __restrict__ ws) {
    const int b = blockIdx.x;
    const int tid = threadIdx.x;
    const int lane = tid & 63, wv = tid >> 6;
    __shared__ unsigned short Cw[(Nn * RBW) / 2 + 32];
    __shared__ int rowBest[Nn + 1];
    __shared__ float Ulds[Nn + 1];
    __shared__ float dvA[192];
    __shared__ float pcm[4][192];
    __shared__ int   pim[4][192];
    __shared__ short rowIdxL[Nn];
    __shared__ float qsL[192];
    __shared__ float ksL[192];
    const float* cg = ws + OFF_COST + (size_t)b * Nn * Nn;   // RAW sim

    const bool v2ok = (lane < Nn - 128);     // lane < 34
    const int id0 = 2 * lane, id1 = 2 * lane + 1, id2 = 128 + lane;
    const int a32 = 4 * lane;
    const int a16 = 256 + 2 * lane;

    if (tid <= Nn) { rowBest[tid] = BIGI; Ulds[tid] = 0.f; }
    if (tid < 192) dvA[tid] = 0.f;

    // ---- fused stats ----
    float* arrS = &pcm[0][0];
    float* thrP = &pcm[1][0];
    float normv = 0.f, mvalv = 0.f;
    if (tid < Nn) {
        float s = 0.f;
        #pragma unroll
        for (int ch = 0; ch < 32; ++ch) s += ws[OFF_P + ((size_t)b * 32 + ch) * 192 + tid];
        normv = sqrtf(s);
        arrS[tid] = normv;
    }
    __syncthreads();   // S1
    {
        float mn = INFV, mx = -INFV;
        for (int k = 0; k < Nn; ++k) { float v = arrS[k]; mn = fminf(mn, v); mx = fmaxf(mx, v); }
        if (tid < Nn) mvalv = (normv - mn) / (mx - mn + 1e-12f);
    }
    __syncthreads();   // S2
    if (tid < Nn) arrS[tid] = mvalv;
    __syncthreads();   // S3
    if (tid < Nn) {
        int cl = 0, ce = 0, ceb = 0;
        for (int k = 0; k < Nn; ++k) {
            float v = arrS[k];
            cl  += (v <  mvalv);
            ce  += (v == mvalv);
            ceb += (v == mvalv && k < tid);
        }
        if (cl <= Pn && (cl + ce) > Pn && ceb == 0) thrP[0] = mvalv;
    }
    if (tid < 192) { qsL[tid] = 0.f; ksL[tid] = 0.f; }
    __syncthreads();   // S4
    if (tid < Nn) {
        float inv = 1.f / fmaxf(normv, 1e-12f);
        ksL[tid] = inv;
        qsL[tid] = (mvalv < thrP[0]) ? 0.f : inv;
    }
    __syncthreads();   // S5

    const float ks0f = ksL[id0];
    const float ks1f = ksL[id1];
    const float ks2f = v2ok ? ksL[id2] : 0.f;

    float aq0 = qsL[lane];
    float aq1 = qsL[64 + lane];
    float aq2 = v2ok ? qsL[128 + lane] : 0.f;
    unsigned long long act0 = __ballot(aq0 != 0.f);
    unsigned long long act1 = __ballot(aq1 != 0.f);
    unsigned long long act2 = __ballot(v2ok && aq2 != 0.f);
    int n0 = __popcll(act0), n1 = __popcll(act1), n2 = __popcll(act2);
    const int nact = n0 + n1 + n2;
    if (nact == 0) { if (tid == 0) ws[OFF_PD + b] = 1.f; return; }

    if (wv == 0) {
        unsigned long long lt = (1ull << lane) - 1;
        if ((act0 >> lane) & 1) rowIdxL[__popcll(act0 & lt)] = (short)lane;
        if ((act1 >> lane) & 1) rowIdxL[n0 + __popcll(act1 & lt)] = (short)(64 + lane);
        if (v2ok && ((act2 >> lane) & 1)) rowIdxL[n0 + n1 + __popcll(act2 & lt)] = (short)(128 + lane);
    }
    __syncthreads();   // B1

    for (int k = wv; k < nact; k += 4) {
        int orig = rowIdxL[k];
        float qsr = qsL[orig];
        float2 f2 = *(const float2*)(cg + (size_t)orig * Nn + 2 * lane);
        unsigned pk = (unsigned)f2h(-(f2.x * qsr * ks0f))
                    | ((unsigned)f2h(-(f2.y * qsr * ks1f)) << 16);
        *(unsigned*)((char*)Cw + k * RBW + a32) = pk;
        if (v2ok) *(unsigned short*)((char*)Cw + k * RBW + a16) =
            f2h(-(cg[(size_t)orig * Nn + 128 + lane] * qsr * ks2f));
    }
    __syncthreads();   // B2

    float cm0 = INFV, cm1 = INFV, cm2 = INFV; int im0 = 0, im1 = 0, im2 = 0;
    for (int k = wv; k < nact; k += 4) {
        unsigned pr = *(const unsigned*)((const char*)Cw + k * RBW + a32);
        float c0 = h2f((unsigned short)pr);
        float c1 = h2f((unsigned short)(pr >> 16));
        float c2 = h2f(*(const unsigned short*)((const char*)Cw + k * RBW + a16));
        if (c0 < cm0) { cm0 = c0; im0 = k + 1; }
        if (c1 < cm1) { cm1 = c1; im1 = k + 1; }
        if (v2ok && c2 < cm2) { cm2 = c2; im2 = k + 1; }
    }
    pcm[wv][id0] = cm0; pim[wv][id0] = im0;
    pcm[wv][id1] = cm1; pim[wv][id1] = im1;
    if (v2ok) { pcm[wv][id2] = cm2; pim[wv][id2] = im2; }
    __syncthreads();   // B3

    cm0 = INFV; im0 = 0; cm1 = INFV; im1 = 0; cm2 = INFV; im2 = 0;
    #pragma unroll
    for (int ww = 0; ww < 4; ++ww) {
        float c; int im;
        c = pcm[ww][id0]; im = pim[ww][id0];
        if (im > 0 && (im0 == 0 || c < cm0 || (c == cm0 && im < im0))) { cm0 = c; im0 = im; }
        c = pcm[ww][id1]; im = pim[ww][id1];
        if (im > 0 && (im1 == 0 || c < cm1 || (c == cm1 && im < im1))) { cm1 = c; im1 = im; }
        if (v2ok) {
            c = pcm[ww][id2]; im = pim[ww][id2];
            if (im > 0 && (im2 == 0 || c < cm2 || (c == cm2 && im < im2))) { cm2 = c; im2 = im; }
        }
    }
    if (wv == 0) {
        if (im0 > 0) atomicMin(&rowBest[im0], id0);
        if (im1 > 0) atomicMin(&rowBest[im1], id1);
        if (v2ok && im2 > 0) atomicMin(&rowBest[im2], id2);
    }
    __syncthreads();   // B4

    float v0 = cm0, v1 = cm1, v2 = v2ok ? cm2 : 0.f;
    int Pa0 = (im0 > 0 && rowBest[im0] == id0) ? im0 : 0;
    int Pa1 = (im1 > 0 && rowBest[im1] == id1) ? im1 : 0;
    int Pa2 = (v2ok && im2 > 0 && rowBest[im2] == id2) ? im2 : 0;

    unsigned long long cb0 = __ballot(lane + 1 <= nact && rowBest[lane + 1] != BIGI);
    unsigned long long cb1 = __ballot(lane + 65 <= nact && rowBest[lane + 65] != BIGI);
    unsigned long long cb2 = __ballot(lane + 129 <= nact && rowBest[lane + 129] != BIGI);
    unsigned long long fr0 = mask_n(nact)       & ~cb0;
    unsigned long long fr1 = mask_n(nact - 64)  & ~cb1;
    unsigned long long fr2 = mask_n(nact - 128) & ~cb2;

    for (int k = wv; k < nact; k += 4) {
        int j1c = rowBest[k + 1];
        if (j1c == BIGI) continue;
        int roff = k * RBW;
        unsigned pr = *(const unsigned*)((const char*)Cw + roff + a32);
        float r0 = h2f((unsigned short)pr) - v0;
        float r1 = h2f((unsigned short)(pr >> 16)) - v1;
        float r2 = h2f(*(const unsigned short*)((const char*)Cw + roff + a16)) - v2;
        unsigned p0 = (id0 == j1c) ? 0xFFFFFFFFu : packnn(r0, id0);
        unsigned p1 = (id1 == j1c) ? 0xFFFFFFFFu : packnn(r1, id1);
        unsigned p2 = (v2ok && id2 != j1c) ? packnn(r2, id2) : 0xFFFFFFFFu;
        unsigned pk = reduceMin64(umin32(p0, umin32(p1, p2)));
        float min2 = unpacknn(pk);
        if (lane == 0) { dvA[j1c] = min2; Ulds[k + 1] = min2; }
    }
    __syncthreads();   // B5 — last barrier; waves 1-3 retire
    if (wv != 0) return;

    float ur0, ur1, ur2;
    v0 -= dvA[id0]; ur0 = dvA[id0];
    v1 -= dvA[id1]; ur1 = dvA[id1];
    if (v2ok) { v2 -= dvA[id2]; ur2 = dvA[id2]; } else ur2 = 0.f;

    float minv0 = INFV, minv1 = INFV, minv2 = INFV;
    int way0 = 255, way1 = 255, way2 = 255;
    bool used0 = false, used1 = false, used2 = false;

    unsigned long long nx0 = 0, nx1 = 0, nx2 = 0;
    int arrIt = 0;
    for (int pass = 0; pass < 2; ++pass) {
        while ((fr0 | fr1 | fr2) != 0 && arrIt < ARRCAP) {
            ++arrIt;
            int i;
            if (fr0)      { int t = __builtin_ctzll(fr0); i = t + 1;   fr0 &= fr0 - 1; }
            else if (fr1) { int t = __builtin_ctzll(fr1); i = t + 65;  fr1 &= fr1 - 1; }
            else          { int t = __builtin_ctzll(fr2); i = t + 129; fr2 &= fr2 - 1; }
            int roff = (i - 1) * RBW;
            unsigned pr = *(const unsigned*)((const char*)Cw + roff + a32);
            float r0 = h2f((unsigned short)pr) - v0;
            float r1 = h2f((unsigned short)(pr >> 16)) - v1;
            float r2 = h2f(*(const unsigned short*)((const char*)Cw + roff + a16)) - v2;
            unsigned p0 = packnn(r0, id0);
            unsigned p1 = packnn(r1, id1);
            unsigned p2 = v2ok ? packnn(r2, id2) : 0xFFFFFFFFu;
            unsigned lmin = umin32(p0, umin32(p1, p2));
            unsigned lmed = umin32(umax32(p0, p1), umax32(umin32(p0, p1), p2));
            unsigned M1 = reduceMin64(lmin);
            unsigned M2 = reduceMin64(lmin == M1 ? lmed : lmin);
            int j1 = (int)(M1 & 0xFFu), j2 = (int)(M2 & 0xFFu);
            int l1 = laneOf(j1), s1 = slotOf(j1);
            int l2 = laneOf(j2), s2 = slotOf(j2);
            float umin_e = rlanef(SEL3(s1, r0, r1, r2), l1);
            float usub_e = rlanef(SEL3(s2, r0, r1, r2), l2);
            int iA = rlanei(SEL3(s1, Pa0, Pa1, Pa2), l1);
            int iB = rlanei(SEL3(s2, Pa0, Pa1, Pa2), l2);
            if (usub_e < umin_e) {
                int tj = j1; j1 = j2; j2 = tj;
                int tl = l1; l1 = l2; l2 = tl;
                int ts = s1; s1 = s2; s2 = ts;
                float tv = umin_e; umin_e = usub_e; usub_e = tv;
                int ti = iA; iA = iB; iB = ti;
            }
            bool strict = (umin_e < usub_e);
            int jt, idisp;
            float ua = usub_e;
            if (strict) {
                float d = usub_e - umin_e;
                if (lane == l1) { if (s1 == 0) v0 -= d; else if (s1 == 1) v1 -= d; else v2 -= d; }
                jt = j1; idisp = iA;
            } else if (iA > 0) {
                jt = j2; idisp = iB;
            } else {
                jt = j1; idisp = 0;
            }
            int lt = laneOf(jt), st = slotOf(jt);
            if (lane == lt) {
                if (st == 0)      { Pa0 = i; ur0 = ua; }
                else if (st == 1) { Pa1 = i; ur1 = ua; }
                else              { Pa2 = i; ur2 = ua; }
            }
            if (lane == 0) Ulds[i] = ua;
            if (idisp > 0) {
                if (strict) {
                    if (idisp <= 64)       fr0 |= 1ull << (idisp - 1);
                    else if (idisp <= 128) fr1 |= 1ull << (idisp - 65);
                    else                   fr2 |= 1ull << (idisp - 129);
                } else {
                    if (idisp <= 64)       nx0 |= 1ull << (idisp - 1);
                    else if (idisp <= 128) nx1 |= 1ull << (idisp - 65);
                    else                   nx2 |= 1ull << (idisp - 129);
                }
            }
        }
        fr0 |= nx0; fr1 |= nx1; fr2 |= nx2;
        nx0 = nx1 = nx2 = 0;
    }

    while ((fr0 | fr1 | fr2) != 0) {
        int i;
        if (fr0)      { int t = __builtin_ctzll(fr0); i = t + 1;   fr0 &= fr0 - 1; }
        else if (fr1) { int t = __builtin_ctzll(fr1); i = t + 65;  fr1 &= fr1 - 1; }
        else          { int t = __builtin_ctzll(fr2); i = t + 129; fr2 &= fr2 - 1; }
        float u_root = Ulds[i];
        minv0 = minv1 = minv2 = INFV;
        way0 = way1 = way2 = 255;
        used0 = used1 = used2 = false;
        {
            int roff = (i - 1) * RBW;
            unsigned pr = *(const unsigned*)((const char*)Cw + roff + a32);
            float c0 = h2f((unsigned short)pr);
            float c1 = h2f((unsigned short)(pr >> 16));
            float c2 = h2f(*(const unsigned short*)((const char*)Cw + roff + a16));
            minv0 = c0 - (u_root + v0);
            minv1 = c1 - (u_root + v1);
            minv2 = v2ok ? (c2 - (u_root + v2)) : INFV;
        }
        int jend = -1;
        for (int it = 0; it < Nn + 2; ++it) {
            unsigned q0p = used0 ? 0xFFFFFFFFu : packnn(minv0, id0);
            unsigned q1p = used1 ? 0xFFFFFFFFu : packnn(minv1, id1);
            unsigned q2p = (v2ok && !used2) ? packnn(minv2, id2) : 0xFFFFFFFFu;
            unsigned pk = reduceMin64(umin32(q0p, umin32(q1p, q2p)));
            int j1 = (int)(pk & 0xFFu);
            float delta = unpacknn(pk);
            int l1 = laneOf(j1), s1 = slotOf(j1);
            int i1 = rlanei(SEL3(s1, Pa0, Pa1, Pa2), l1);
            float u1 = rlanef(SEL3(s1, ur0, ur1, ur2), l1);
            u_root += delta;
            v0 = used0 ? v0 - delta : v0;  ur0 = used0 ? ur0 + delta : ur0;  minv0 = used0 ? minv0 : minv0 - delta;
            v1 = used1 ? v1 - delta : v1;  ur1 = used1 ? ur1 + delta : ur1;  minv1 = used1 ? minv1 : minv1 - delta;
            v2 = used2 ? v2 - delta : v2;  ur2 = used2 ? ur2 + delta : ur2;  minv2 = used2 ? minv2 : minv2 - delta;
            bool hit = (lane == l1);
            if (s1 == 0) used0 |= hit; else if (s1 == 1) used1 |= hit; else used2 |= hit;
            if (i1 == 0) { jend = j1; break; }
            int roff = (i1 - 1) * RBW;
            unsigned pr = *(const unsigned*)((const char*)Cw + roff + a32);
            float c0 = h2f((unsigned short)pr);
            float c1 = h2f((unsigned short)(pr >> 16));
            float c2 = h2f(*(const unsigned short*)((const char*)Cw + roff + a16));
            float n0_ = c0 - (u1 + v0), n1_ = c1 - (u1 + v1), n2_ = c2 - (u1 + v2);
            if (!used0 && n0_ < minv0) { minv0 = n0_; way0 = j1; }
            if (!used1 && n1_ < minv1) { minv1 = n1_; way1 = j1; }
            if (v2ok && !used2 && n2_ < minv2) { minv2 = n2_; way2 = j1; }
        }
        int j = jend;
        while (j >= 0) {
            int l = laneOf(j), s = slotOf(j);
            int w = rlanei(SEL3(s, way0, way1, way2), l);
            int pnew; float unew;
            if (w == 255) { pnew = i; unew = u_root; }
            else {
                int lw = laneOf(w), sw = slotOf(w);
                pnew = rlanei(SEL3(sw, Pa0, Pa1, Pa2), lw);
                unew = rlanef(SEL3(sw, ur0, ur1, ur2), lw);
            }
            if (lane == l) {
                if (s == 0)      { Pa0 = pnew; ur0 = unew; }
                else if (s == 1) { Pa1 = pnew; ur1 = unew; }
                else             { Pa2 = pnew; ur2 = unew; }
            }
            j = (w == 255) ? -1 : w;
        }
    }

    float tot = 0.f;
    if (Pa0 > 0) { int orig = rowIdxL[Pa0 - 1]; tot += cg[(size_t)orig * Nn + id0] * qsL[orig] * ks0f; }
    if (Pa1 > 0) { int orig = rowIdxL[Pa1 - 1]; tot += cg[(size_t)orig * Nn + id1] * qsL[orig] * ks1f; }
    if (v2ok && Pa2 > 0) { int orig = rowIdxL[Pa2 - 1]; tot += cg[(size_t)orig * Nn + id2] * qsL[orig] * ks2f; }
    #pragma unroll
    for (int off = 32; off; off >>= 1) tot += __shfl_xor(tot, off);
    if (lane == 0) ws[OFF_PD + b] = 1.f - tot * (1.f / (float)Pn);
}

// ---------------- K4: mean over batches ----------------
__global__ void k_final(const float* __restrict__ ws, float* __restrict__ out) {
    float v = ws[OFF_PD + threadIdx.x];
    #pragma unroll
    for (int off = 32; off; off >>= 1) v += __shfl_xor(v, off);
    if (threadIdx.x == 0) out[0] = v * (1.f / 64.f);
}

extern "C" void kernel_launch(void* const* d_in, const int* in_sizes, int n_in,
                              void* d_out, int out_size, void* d_ws, size_t ws_size,
                              hipStream_t stream) {
    const float* feat = (const float*)d_in[0];
    const int*   pos  = (const int*)d_in[1];
    float* ws  = (float*)d_ws;
    float* out = (float*)d_out;
    k_tr   <<<dim3(32, 64), 256, 0, stream>>>(feat, ws);
    k_mm   <<<384, 256, 0, stream>>>(pos, ws);
    k_hung <<<64, 256, 0, stream>>>(ws);
    k_final<<<1, 64, 0, stream>>>(ws, out);
}

// Round 14
// 101.795 us; speedup vs baseline: 1.0530x; 1.0530x over previous
//
#include <hip/hip_runtime.h>
#include <hip/hip_bf16.h>

#define Bn 64
#define Cn 2048
#define Nn 162          // H*W = 18*9
#define Pn 81           // Nn/2
#define NP 176          // padded N for featT rows (11 tiles of 16)
#define INFV 1.0e9f
#define BIGI 0x7FFFFFFF
#define RBW 328         // k_hung LDS cost-row stride BYTES
#define ARRCAP 700

// ws layout (in floats)
// featT layout: [b][cc(32)][gcol(NP)][32 u32]  (cc = 64-channel chunk)
#define OFF_T    0                           // bf16 featT = 11,534,336 floats
#define OFF_P    11534336                    // [64][32][192] norm^2 partials
#define OFF_QS   (OFF_P + 64*32*192)         // (unused, layout keep)
#define OFF_KS   (OFF_QS + 64*162)           // (unused, layout keep)
#define OFF_COST (OFF_KS + 64*162)           // [64][162][162] RAW sim (fp32)
#define OFF_PD   (OFF_COST + 64*162*162)     // [64] per-batch pos_dis; +64 = int counter

typedef __attribute__((ext_vector_type(8))) short bf16x8;
typedef __attribute__((ext_vector_type(4))) float f32x4;
typedef __attribute__((ext_vector_type(4))) unsigned u32x4;

static __device__ __forceinline__ unsigned short f2bf(float x) {
    unsigned int u = __builtin_bit_cast(unsigned int, x);
    unsigned int r = (u + 0x7fffu + ((u >> 16) & 1u)) >> 16;   // RNE
    return (unsigned short)r;
}
static __device__ __forceinline__ unsigned short f2h(float x) {
    _Float16 h = (_Float16)x;
    return __builtin_bit_cast(unsigned short, h);
}
static __device__ __forceinline__ float h2f(unsigned short u) {
    return (float)__builtin_bit_cast(_Float16, u);
}
static __device__ __forceinline__ unsigned umin32(unsigned a, unsigned b) { return a < b ? a : b; }
static __device__ __forceinline__ unsigned umax32(unsigned a, unsigned b) { return a > b ? a : b; }
static __device__ __forceinline__ unsigned packnn(float v, int id) {
    float c = fmaxf(v, 0.f);
    return (__builtin_bit_cast(unsigned, c) & 0xFFFFFF00u) | (unsigned)id;
}
static __device__ __forceinline__ float unpacknn(unsigned pk) {
    return __builtin_bit_cast(float, pk & 0xFFFFFF00u);
}
static __device__ __forceinline__ unsigned reduceMin64(unsigned x) {
    int v = (int)x, t;
    t = __builtin_amdgcn_update_dpp(0, v, 0x121, 0xF, 0xF, true); v = (int)umin32((unsigned)v, (unsigned)t);
    t = __builtin_amdgcn_update_dpp(0, v, 0x122, 0xF, 0xF, true); v = (int)umin32((unsigned)v, (unsigned)t);
    t = __builtin_amdgcn_update_dpp(0, v, 0x124, 0xF, 0xF, true); v = (int)umin32((unsigned)v, (unsigned)t);
    t = __builtin_amdgcn_update_dpp(0, v, 0x128, 0xF, 0xF, true); v = (int)umin32((unsigned)v, (unsigned)t);
    unsigned a = (unsigned)__builtin_amdgcn_readlane(v, 0);
    unsigned b = (unsigned)__builtin_amdgcn_readlane(v, 16);
    unsigned c = (unsigned)__builtin_amdgcn_readlane(v, 32);
    unsigned d = (unsigned)__builtin_amdgcn_readlane(v, 48);
    return umin32(umin32(a, b), umin32(c, d));
}
static __device__ __forceinline__ int rlanei(int v, int l) { return __builtin_amdgcn_readlane(v, l); }
static __device__ __forceinline__ float rlanef(float v, int l) {
    return __builtin_bit_cast(float, __builtin_amdgcn_readlane(__builtin_bit_cast(int, v), l));
}
static __device__ __forceinline__ int laneOf(int id) { return id < 128 ? (id >> 1) : (id - 128); }
static __device__ __forceinline__ int slotOf(int id) { return id < 128 ? (id & 1) : 2; }
static __device__ __forceinline__ unsigned long long mask_n(int n) {
    if (n <= 0) return 0ull;
    if (n >= 64) return ~0ull;
    return (1ull << n) - 1ull;
}
#define SEL3(s, a0, a1, a2) ((s) == 0 ? (a0) : ((s) == 1 ? (a1) : (a2)))

// Device-scope fused finalization (replaces k_final). All cross-block data
// moves through atomics (XCD-L2-coherence safe); fixed butterfly => deterministic.
static __device__ __forceinline__ void finalize(float* ws, float* out, int b, float pdval, int lane) {
    int old = 0;
    if (lane == 0) {
        atomicExch(ws + OFF_PD + b, pdval);
        __threadfence();
        old = atomicAdd((int*)(ws + OFF_PD + 64), 1);
    }
    old = rlanei(old, 0);
    if (old == 63) {                       // last batch-block: reduce all 64
        __threadfence();
        float v = atomicAdd(ws + OFF_PD + lane, 0.f);   // coherent load via RMW
        #pragma unroll
        for (int off = 32; off; off >>= 1) v += __shfl_xor(v, off);
        if (lane == 0) out[0] = v * (1.f / 64.f);
    }
}

// ---------------- K1: pack-at-load transpose + norm^2, contiguous writes (R12) ----------------
__global__ __launch_bounds__(256) void k_tr(const float* __restrict__ feat, float* __restrict__ ws) {
    int x = blockIdx.x;            // 0..95: cc = ch-chunk (32), ct = col-chunk (3)
    int cc = x / 3, ct = x % 3;
    int b = blockIdx.y;
    int tid = threadIdx.x;
    if (x == 0 && b == 0 && tid == 0) *(int*)(ws + OFF_PD + 64) = 0;   // arm finalize counter
    int c2 = tid & 31, pg = tid >> 5;         // col-pair 0..31, p-group 0..7
    __shared__ unsigned Tp[32][65];           // packed bf16 ch-pairs [p][col]
    __shared__ float Pp[8][64];               // norm^2 partials
    int gc0 = ct * 64 + 2 * c2;
    bool ok  = (gc0 < Nn);
    bool ok1 = (gc0 + 1 < Nn);
    int gcs = ok ? gc0 : 0;
    const float* fb = feat + ((size_t)b * Cn + (size_t)cc * 64) * Nn;
    float2 fa[4], fc[4];
    #pragma unroll
    for (int it = 0; it < 4; ++it) {
        int p = pg + it * 8;
        fa[it] = *(const float2*)(fb + (size_t)(2 * p) * Nn + gcs);
        fc[it] = *(const float2*)(fb + (size_t)(2 * p + 1) * Nn + gcs);
    }
    float s0 = 0.f, s1 = 0.f;
    #pragma unroll
    for (int it = 0; it < 4; ++it) {
        int p = pg + it * 8;
        float ax = ok  ? fa[it].x : 0.f;
        float ay = ok1 ? fa[it].y : 0.f;
        float cx = ok  ? fc[it].x : 0.f;
        float cy = ok1 ? fc[it].y : 0.f;
        s0 = fmaf(ax, ax, fmaf(cx, cx, s0));
        s1 = fmaf(ay, ay, fmaf(cy, cy, s1));
        Tp[p][2 * c2]     = (unsigned)f2bf(ax) | ((unsigned)f2bf(cx) << 16);
        Tp[p][2 * c2 + 1] = (unsigned)f2bf(ay) | ((unsigned)f2bf(cy) << 16);
    }
    Pp[pg][2 * c2]     = s0;
    Pp[pg][2 * c2 + 1] = s1;
    __syncthreads();
    if (tid < 64) {
        float t = 0.f;
        #pragma unroll
        for (int g = 0; g < 8; ++g) t += Pp[g][tid];
        ws[OFF_P + ((size_t)b * 32 + cc) * 192 + ct * 64 + tid] = t;
    }
    unsigned* ft = (unsigned*)(ws + OFF_T);
    size_t base = ((size_t)(b * 32 + cc) * NP + ct * 64) * 32;
    #pragma unroll
    for (int it = 0; it < 8; ++it) {
        int idx = it * 256 + tid;
        int c = idx >> 5;
        int gcol = ct * 64 + c;
        if (gcol < NP) ft[base + idx] = Tp[idx & 31][c];
    }
}

// ---------------- K2: bf16 MFMA GEMM from featT -> RAW sim ----------------
__global__ __launch_bounds__(256) void k_mm(const int* __restrict__ pos_ind,
                                            float* __restrict__ ws) {
    int wg = blockIdx.x;
    int xcd = wg & 7, kk = wg >> 3;
    int b  = xcd + 8 * (kk / 6);
    int mt = kk % 6;
    int tid = threadIdx.x;
    int lane = tid & 63, w = tid >> 6;
    int q0 = mt * 32;
    int pb = pos_ind[b];
    const u32x4* At = (const u32x4*)((const unsigned short*)(ws + OFF_T) + (size_t)b  * NP * Cn);
    const u32x4* Bt = (const u32x4*)((const unsigned short*)(ws + OFF_T) + (size_t)pb * NP * Cn);
    __shared__ u32x4 As[32 * 16];      // 8 KB
    __shared__ u32x4 Bs[176 * 16];     // 44 KB

    f32x4 a00 = {0.f, 0.f, 0.f, 0.f}, a01 = a00, a02 = a00, a10 = a00, a11 = a00, a12 = a00;
    const int ct0 = w * 3, ct1 = w * 3 + 1, ct2 = w * 3 + 2;
    const bool has2 = (ct2 < 11);
    const int fr = lane & 15, fq = lane >> 4;

    for (int c0 = 0; c0 < Cn; c0 += 128) {
        int cc0 = c0 >> 6;
        #pragma unroll
        for (int it = 0; it < 2; ++it) {
            int task = it * 256 + tid;
            int r = task >> 4, g = task & 15;
            int rowc = q0 + r; if (rowc > NP - 1) rowc = NP - 1;
            As[r * 16 + (g ^ (r & 15))] = At[((size_t)(cc0 + (g >> 3)) * NP + rowc) * 8 + (g & 7)];
        }
        #pragma unroll
        for (int it = 0; it < 11; ++it) {
            int task = it * 256 + tid;
            int col = task >> 4, g = task & 15;
            Bs[col * 16 + (g ^ (col & 15))] = Bt[((size_t)(cc0 + (g >> 3)) * NP + col) * 8 + (g & 7)];
        }
        __syncthreads();
        #pragma unroll
        for (int ks = 0; ks < 4; ++ks) {
            int gk = ks * 4 + fq;
            bf16x8 af0 = *(const bf16x8*)&As[fr * 16 + (gk ^ fr)];
            bf16x8 af1 = *(const bf16x8*)&As[(16 + fr) * 16 + (gk ^ fr)];
            bf16x8 b0 = *(const bf16x8*)&Bs[(ct0 * 16 + fr) * 16 + (gk ^ fr)];
            bf16x8 b1 = *(const bf16x8*)&Bs[(ct1 * 16 + fr) * 16 + (gk ^ fr)];
            a00 = __builtin_amdgcn_mfma_f32_16x16x32_bf16(af0, b0, a00, 0, 0, 0);
            a01 = __builtin_amdgcn_mfma_f32_16x16x32_bf16(af0, b1, a01, 0, 0, 0);
            a10 = __builtin_amdgcn_mfma_f32_16x16x32_bf16(af1, b0, a10, 0, 0, 0);
            a11 = __builtin_amdgcn_mfma_f32_16x16x32_bf16(af1, b1, a11, 0, 0, 0);
            if (has2) {
                bf16x8 b2 = *(const bf16x8*)&Bs[(ct2 * 16 + fr) * 16 + (gk ^ fr)];
                a02 = __builtin_amdgcn_mfma_f32_16x16x32_bf16(af0, b2, a02, 0, 0, 0);
                a12 = __builtin_amdgcn_mfma_f32_16x16x32_bf16(af1, b2, a12, 0, 0, 0);
            }
        }
        __syncthreads();
    }

    float* simg = ws + OFF_COST + (size_t)b * Nn * Nn;
    int c0_ = ct0 * 16 + fr, c1_ = ct1 * 16 + fr, c2_ = ct2 * 16 + fr;
    #pragma unroll
    for (int j = 0; j < 4; ++j) {
        int r0 = q0 + fq * 4 + j;
        int r1 = r0 + 16;
        if (r0 < Nn) {
            if (c0_ < Nn) simg[(size_t)r0 * Nn + c0_] = a00[j];
            if (c1_ < Nn) simg[(size_t)r0 * Nn + c1_] = a01[j];
            if (has2 && c2_ < Nn) simg[(size_t)r0 * Nn + c2_] = a02[j];
        }
        if (r1 < Nn) {
            if (c0_ < Nn) simg[(size_t)r1 * Nn + c0_] = a10[j];
            if (c1_ < Nn) simg[(size_t)r1 * Nn + c1_] = a11[j];
            if (has2 && c2_ < Nn) simg[(size_t)r1 * Nn + c2_] = a12[j];
        }
    }
}

// ---------------- K3: fused stats + rectangular LAPJV + final mean ----------------
__global__ __launch_bounds__(256) void k_hung(float* __restrict__ ws, float* __restrict__ out) {
    const int b = blockIdx.x;
    const int tid = threadIdx.x;
    const int lane = tid & 63, wv = tid >> 6;
    __shared__ unsigned short Cw[(Nn * RBW) / 2 + 32];
    __shared__ int rowBest[Nn + 1];
    __shared__ float Ulds[Nn + 1];
    __shared__ float dvA[192];
    __shared__ float pcm[4][192];
    __shared__ int   pim[4][192];
    __shared__ short rowIdxL[Nn];
    __shared__ float qsL[192];
    __shared__ float ksL[192];
    const float* cg = ws + OFF_COST + (size_t)b * Nn * Nn;   // RAW sim

    const bool v2ok = (lane < Nn - 128);     // lane < 34
    const int id0 = 2 * lane, id1 = 2 * lane + 1, id2 = 128 + lane;
    const int a32 = 4 * lane;
    const int a16 = 256 + 2 * lane;

    if (tid <= Nn) { rowBest[tid] = BIGI; Ulds[tid] = 0.f; }
    if (tid < 192) dvA[tid] = 0.f;

    // ---- fused stats ----
    float* arrS = &pcm[0][0];
    float* thrP = &pcm[1][0];
    float normv = 0.f, mvalv = 0.f;
    if (tid < Nn) {
        float s = 0.f;
        #pragma unroll
        for (int ch = 0; ch < 32; ++ch) s += ws[OFF_P + ((size_t)b * 32 + ch) * 192 + tid];
        normv = sqrtf(s);
        arrS[tid] = normv;
    }
    __syncthreads();   // S1
    {
        float mn = INFV, mx = -INFV;
        for (int k = 0; k < Nn; ++k) { float v = arrS[k]; mn = fminf(mn, v); mx = fmaxf(mx, v); }
        if (tid < Nn) mvalv = (normv - mn) / (mx - mn + 1e-12f);
    }
    __syncthreads();   // S2
    if (tid < Nn) arrS[tid] = mvalv;
    __syncthreads();   // S3
    if (tid < Nn) {
        int cl = 0, ce = 0, ceb = 0;
        for (int k = 0; k < Nn; ++k) {
            float v = arrS[k];
            cl  += (v <  mvalv);
            ce  += (v == mvalv);
            ceb += (v == mvalv && k < tid);
        }
        if (cl <= Pn && (cl + ce) > Pn && ceb == 0) thrP[0] = mvalv;
    }
    if (tid < 192) { qsL[tid] = 0.f; ksL[tid] = 0.f; }
    __syncthreads();   // S4
    if (tid < Nn) {
        float inv = 1.f / fmaxf(normv, 1e-12f);
        ksL[tid] = inv;
        qsL[tid] = (mvalv < thrP[0]) ? 0.f : inv;
    }
    __syncthreads();   // S5

    const float ks0f = ksL[id0];
    const float ks1f = ksL[id1];
    const float ks2f = v2ok ? ksL[id2] : 0.f;

    float aq0 = qsL[lane];
    float aq1 = qsL[64 + lane];
    float aq2 = v2ok ? qsL[128 + lane] : 0.f;
    unsigned long long act0 = __ballot(aq0 != 0.f);
    unsigned long long act1 = __ballot(aq1 != 0.f);
    unsigned long long act2 = __ballot(v2ok && aq2 != 0.f);
    int n0 = __popcll(act0), n1 = __popcll(act1), n2 = __popcll(act2);
    const int nact = n0 + n1 + n2;
    if (nact == 0) {
        if (wv == 0) finalize(ws, out, b, 1.f, lane);
        return;
    }

    if (wv == 0) {
        unsigned long long lt = (1ull << lane) - 1;
        if ((act0 >> lane) & 1) rowIdxL[__popcll(act0 & lt)] = (short)lane;
        if ((act1 >> lane) & 1) rowIdxL[n0 + __popcll(act1 & lt)] = (short)(64 + lane);
        if (v2ok && ((act2 >> lane) & 1)) rowIdxL[n0 + n1 + __popcll(act2 & lt)] = (short)(128 + lane);
    }
    __syncthreads();   // B1

    for (int k = wv; k < nact; k += 4) {
        int orig = rowIdxL[k];
        float qsr = qsL[orig];
        float2 f2 = *(const float2*)(cg + (size_t)orig * Nn + 2 * lane);
        unsigned pk = (unsigned)f2h(-(f2.x * qsr * ks0f))
                    | ((unsigned)f2h(-(f2.y * qsr * ks1f)) << 16);
        *(unsigned*)((char*)Cw + k * RBW + a32) = pk;
        if (v2ok) *(unsigned short*)((char*)Cw + k * RBW + a16) =
            f2h(-(cg[(size_t)orig * Nn + 128 + lane] * qsr * ks2f));
    }
    __syncthreads();   // B2

    float cm0 = INFV, cm1 = INFV, cm2 = INFV; int im0 = 0, im1 = 0, im2 = 0;
    for (int k = wv; k < nact; k += 4) {
        unsigned pr = *(const unsigned*)((const char*)Cw + k * RBW + a32);
        float c0 = h2f((unsigned short)pr);
        float c1 = h2f((unsigned short)(pr >> 16));
        float c2 = h2f(*(const unsigned short*)((const char*)Cw + k * RBW + a16));
        if (c0 < cm0) { cm0 = c0; im0 = k + 1; }
        if (c1 < cm1) { cm1 = c1; im1 = k + 1; }
        if (v2ok && c2 < cm2) { cm2 = c2; im2 = k + 1; }
    }
    pcm[wv][id0] = cm0; pim[wv][id0] = im0;
    pcm[wv][id1] = cm1; pim[wv][id1] = im1;
    if (v2ok) { pcm[wv][id2] = cm2; pim[wv][id2] = im2; }
    __syncthreads();   // B3

    cm0 = INFV; im0 = 0; cm1 = INFV; im1 = 0; cm2 = INFV; im2 = 0;
    #pragma unroll
    for (int ww = 0; ww < 4; ++ww) {
        float c; int im;
        c = pcm[ww][id0]; im = pim[ww][id0];
        if (im > 0 && (im0 == 0 || c < cm0 || (c == cm0 && im < im0))) { cm0 = c; im0 = im; }
        c = pcm[ww][id1]; im = pim[ww][id1];
        if (im > 0 && (im1 == 0 || c < cm1 || (c == cm1 && im < im1))) { cm1 = c; im1 = im; }
        if (v2ok) {
            c = pcm[ww][id2]; im = pim[ww][id2];
            if (im > 0 && (im2 == 0 || c < cm2 || (c == cm2 && im < im2))) { cm2 = c; im2 = im; }
        }
    }
    if (wv == 0) {
        if (im0 > 0) atomicMin(&rowBest[im0], id0);
        if (im1 > 0) atomicMin(&rowBest[im1], id1);
        if (v2ok && im2 > 0) atomicMin(&rowBest[im2], id2);
    }
    __syncthreads();   // B4

    float v0 = cm0, v1 = cm1, v2 = v2ok ? cm2 : 0.f;
    int Pa0 = (im0 > 0 && rowBest[im0] == id0) ? im0 : 0;
    int Pa1 = (im1 > 0 && rowBest[im1] == id1) ? im1 : 0;
    int Pa2 = (v2ok && im2 > 0 && rowBest[im2] == id2) ? im2 : 0;

    unsigned long long cb0 = __ballot(lane + 1 <= nact && rowBest[lane + 1] != BIGI);
    unsigned long long cb1 = __ballot(lane + 65 <= nact && rowBest[lane + 65] != BIGI);
    unsigned long long cb2 = __ballot(lane + 129 <= nact && rowBest[lane + 129] != BIGI);
    unsigned long long fr0 = mask_n(nact)       & ~cb0;
    unsigned long long fr1 = mask_n(nact - 64)  & ~cb1;
    unsigned long long fr2 = mask_n(nact - 128) & ~cb2;

    for (int k = wv; k < nact; k += 4) {
        int j1c = rowBest[k + 1];
        if (j1c == BIGI) continue;
        int roff = k * RBW;
        unsigned pr = *(const unsigned*)((const char*)Cw + roff + a32);
        float r0 = h2f((unsigned short)pr) - v0;
        float r1 = h2f((unsigned short)(pr >> 16)) - v1;
        float r2 = h2f(*(const unsigned short*)((const char*)Cw + roff + a16)) - v2;
        unsigned p0 = (id0 == j1c) ? 0xFFFFFFFFu : packnn(r0, id0);
        unsigned p1 = (id1 == j1c) ? 0xFFFFFFFFu : packnn(r1, id1);
        unsigned p2 = (v2ok && id2 != j1c) ? packnn(r2, id2) : 0xFFFFFFFFu;
        unsigned pk = reduceMin64(umin32(p0, umin32(p1, p2)));
        float min2 = unpacknn(pk);
        if (lane == 0) { dvA[j1c] = min2; Ulds[k + 1] = min2; }
    }
    __syncthreads();   // B5 — last barrier; waves 1-3 retire
    if (wv != 0) return;

    float ur0, ur1, ur2;
    v0 -= dvA[id0]; ur0 = dvA[id0];
    v1 -= dvA[id1]; ur1 = dvA[id1];
    if (v2ok) { v2 -= dvA[id2]; ur2 = dvA[id2]; } else ur2 = 0.f;

    float minv0 = INFV, minv1 = INFV, minv2 = INFV;
    int way0 = 255, way1 = 255, way2 = 255;
    bool used0 = false, used1 = false, used2 = false;

    unsigned long long nx0 = 0, nx1 = 0, nx2 = 0;
    int arrIt = 0;
    for (int pass = 0; pass < 2; ++pass) {
        while ((fr0 | fr1 | fr2) != 0 && arrIt < ARRCAP) {
            ++arrIt;
            int i;
            if (fr0)      { int t = __builtin_ctzll(fr0); i = t + 1;   fr0 &= fr0 - 1; }
            else if (fr1) { int t = __builtin_ctzll(fr1); i = t + 65;  fr1 &= fr1 - 1; }
            else          { int t = __builtin_ctzll(fr2); i = t + 129; fr2 &= fr2 - 1; }
            int roff = (i - 1) * RBW;
            unsigned pr = *(const unsigned*)((const char*)Cw + roff + a32);
            float r0 = h2f((unsigned short)pr) - v0;
            float r1 = h2f((unsigned short)(pr >> 16)) - v1;
            float r2 = h2f(*(const unsigned short*)((const char*)Cw + roff + a16)) - v2;
            unsigned p0 = packnn(r0, id0);
            unsigned p1 = packnn(r1, id1);
            unsigned p2 = v2ok ? packnn(r2, id2) : 0xFFFFFFFFu;
            unsigned lmin = umin32(p0, umin32(p1, p2));
            unsigned lmed = umin32(umax32(p0, p1), umax32(umin32(p0, p1), p2));
            unsigned M1 = reduceMin64(lmin);
            unsigned M2 = reduceMin64(lmin == M1 ? lmed : lmin);
            int j1 = (int)(M1 & 0xFFu), j2 = (int)(M2 & 0xFFu);
            int l1 = laneOf(j1), s1 = slotOf(j1);
            int l2 = laneOf(j2), s2 = slotOf(j2);
            float umin_e = rlanef(SEL3(s1, r0, r1, r2), l1);
            float usub_e = rlanef(SEL3(s2, r0, r1, r2), l2);
            int iA = rlanei(SEL3(s1, Pa0, Pa1, Pa2), l1);
            int iB = rlanei(SEL3(s2, Pa0, Pa1, Pa2), l2);
            if (usub_e < umin_e) {
                int tj = j1; j1 = j2; j2 = tj;
                int tl = l1; l1 = l2; l2 = tl;
                int ts = s1; s1 = s2; s2 = ts;
                float tv = umin_e; umin_e = usub_e; usub_e = tv;
                int ti = iA; iA = iB; iB = ti;
            }
            bool strict = (umin_e < usub_e);
            int jt, idisp;
            float ua = usub_e;
            if (strict) {
                float d = usub_e - umin_e;
                if (lane == l1) { if (s1 == 0) v0 -= d; else if (s1 == 1) v1 -= d; else v2 -= d; }
                jt = j1; idisp = iA;
            } else if (iA > 0) {
                jt = j2; idisp = iB;
            } else {
                jt = j1; idisp = 0;
            }
            int lt = laneOf(jt), st = slotOf(jt);
            if (lane == lt) {
                if (st == 0)      { Pa0 = i; ur0 = ua; }
                else if (st == 1) { Pa1 = i; ur1 = ua; }
                else              { Pa2 = i; ur2 = ua; }
            }
            if (lane == 0) Ulds[i] = ua;
            if (idisp > 0) {
                if (strict) {
                    if (idisp <= 64)       fr0 |= 1ull << (idisp - 1);
                    else if (idisp <= 128) fr1 |= 1ull << (idisp - 65);
                    else                   fr2 |= 1ull << (idisp - 129);
                } else {
                    if (idisp <= 64)       nx0 |= 1ull << (idisp - 1);
                    else if (idisp <= 128) nx1 |= 1ull << (idisp - 65);
                    else                   nx2 |= 1ull << (idisp - 129);
                }
            }
        }
        fr0 |= nx0; fr1 |= nx1; fr2 |= nx2;
        nx0 = nx1 = nx2 = 0;
    }

    while ((fr0 | fr1 | fr2) != 0) {
        int i;
        if (fr0)      { int t = __builtin_ctzll(fr0); i = t + 1;   fr0 &= fr0 - 1; }
        else if (fr1) { int t = __builtin_ctzll(fr1); i = t + 65;  fr1 &= fr1 - 1; }
        else          { int t = __builtin_ctzll(fr2); i = t + 129; fr2 &= fr2 - 1; }
        float u_root = Ulds[i];
        minv0 = minv1 = minv2 = INFV;
        way0 = way1 = way2 = 255;
        used0 = used1 = used2 = false;
        {
            int roff = (i - 1) * RBW;
            unsigned pr = *(const unsigned*)((const char*)Cw + roff + a32);
            float c0 = h2f((unsigned short)pr);
            float c1 = h2f((unsigned short)(pr >> 16));
            float c2 = h2f(*(const unsigned short*)((const char*)Cw + roff + a16));
            minv0 = c0 - (u_root + v0);
            minv1 = c1 - (u_root + v1);
            minv2 = v2ok ? (c2 - (u_root + v2)) : INFV;
        }
        int jend = -1;
        for (int it = 0; it < Nn + 2; ++it) {
            unsigned q0p = used0 ? 0xFFFFFFFFu : packnn(minv0, id0);
            unsigned q1p = used1 ? 0xFFFFFFFFu : packnn(minv1, id1);
            unsigned q2p = (v2ok && !used2) ? packnn(minv2, id2) : 0xFFFFFFFFu;
            unsigned pk = reduceMin64(umin32(q0p, umin32(q1p, q2p)));
            int j1 = (int)(pk & 0xFFu);
            float delta = unpacknn(pk);
            int l1 = laneOf(j1), s1 = slotOf(j1);
            int i1 = rlanei(SEL3(s1, Pa0, Pa1, Pa2), l1);
            float u1 = rlanef(SEL3(s1, ur0, ur1, ur2), l1);
            u_root += delta;
            v0 = used0 ? v0 - delta : v0;  ur0 = used0 ? ur0 + delta : ur0;  minv0 = used0 ? minv0 : minv0 - delta;
            v1 = used1 ? v1 - delta : v1;  ur1 = used1 ? ur1 + delta : ur1;  minv1 = used1 ? minv1 : minv1 - delta;
            v2 = used2 ? v2 - delta : v2;  ur2 = used2 ? ur2 + delta : ur2;  minv2 = used2 ? minv2 : minv2 - delta;
            bool hit = (lane == l1);
            if (s1 == 0) used0 |= hit; else if (s1 == 1) used1 |= hit; else used2 |= hit;
            if (i1 == 0) { jend = j1; break; }
            int roff = (i1 - 1) * RBW;
            unsigned pr = *(const unsigned*)((const char*)Cw + roff + a32);
            float c0 = h2f((unsigned short)pr);
            float c1 = h2f((unsigned short)(pr >> 16));
            float c2 = h2f(*(const unsigned short*)((const char*)Cw + roff + a16));
            float n0_ = c0 - (u1 + v0), n1_ = c1 - (u1 + v1), n2_ = c2 - (u1 + v2);
            if (!used0 && n0_ < minv0) { minv0 = n0_; way0 = j1; }
            if (!used1 && n1_ < minv1) { minv1 = n1_; way1 = j1; }
            if (v2ok && !used2 && n2_ < minv2) { minv2 = n2_; way2 = j1; }
        }
        int j = jend;
        while (j >= 0) {
            int l = laneOf(j), s = slotOf(j);
            int w = rlanei(SEL3(s, way0, way1, way2), l);
            int pnew; float unew;
            if (w == 255) { pnew = i; unew = u_root; }
            else {
                int lw = laneOf(w), sw = slotOf(w);
                pnew = rlanei(SEL3(sw, Pa0, Pa1, Pa2), lw);
                unew = rlanef(SEL3(sw, ur0, ur1, ur2), lw);
            }
            if (lane == l) {
                if (s == 0)      { Pa0 = pnew; ur0 = unew; }
                else if (s == 1) { Pa1 = pnew; ur1 = unew; }
                else             { Pa2 = pnew; ur2 = unew; }
            }
            j = (w == 255) ? -1 : w;
        }
    }

    float tot = 0.f;
    if (Pa0 > 0) { int orig = rowIdxL[Pa0 - 1]; tot += cg[(size_t)orig * Nn + id0] * qsL[orig] * ks0f; }
    if (Pa1 > 0) { int orig = rowIdxL[Pa1 - 1]; tot += cg[(size_t)orig * Nn + id1] * qsL[orig] * ks1f; }
    if (v2ok && Pa2 > 0) { int orig = rowIdxL[Pa2 - 1]; tot += cg[(size_t)orig * Nn + id2] * qsL[orig] * ks2f; }
    #pragma unroll
    for (int off = 32; off; off >>= 1) tot += __shfl_xor(tot, off);
    finalize(ws, out, b, 1.f - tot * (1.f / (float)Pn), lane);
}

extern "C" void kernel_launch(void* const* d_in, const int* in_sizes, int n_in,
                              void* d_out, int out_size, void* d_ws, size_t ws_size,
                              hipStream_t stream) {
    const float* feat = (const float*)d_in[0];
    const int*   pos  = (const int*)d_in[1];
    float* ws  = (float*)d_ws;
    float* out = (float*)d_out;
    k_tr   <<<dim3(96, 64), 256, 0, stream>>>(feat, ws);
    k_mm   <<<384, 256, 0, stream>>>(pos, ws);
    k_hung <<<64, 256, 0, stream>>>(ws, out);
}